// Round 3
// baseline (561.119 us; speedup 1.0000x reference)
//
#include <hip/hip_runtime.h>
#include <hip/hip_bf16.h>

// FFM interaction layer: out[b, p, e] = in[b, jj[p]*20+ii[p], e] * in[b, ii[p]*20+jj[p], e]
// B=4096, N=20, E=64, P=190. Pure gather+multiply, memory-bound.
// Ideal HBM traffic: 398 MB read + 199 MB write => ~95 us at 6.3 TB/s.

#define N_FIELDS 20
#define N_PAIRS  190           // 20*19/2
#define EMBED    64
#define BATCH    4096
#define ROW_F4   16            // 64 floats = 16 float4 per row
#define IN_ROWS  400           // N*N rows per batch
#define IN_F4    (IN_ROWS * ROW_F4)    // 6400 float4 per batch
#define OUT_F4   (N_PAIRS * ROW_F4)    // 3040 float4 per batch

// Clang-native vector type: required by __builtin_nontemporal_* (HIP's float4
// is a struct and is rejected). Lowers to global_{load,store}_dwordx4 nt.
typedef float f32x4 __attribute__((ext_vector_type(4)));

// Compile-time pair table: rows[p] = (rowA << 16) | rowB where
// rowA = j*20+i (factor v[:, j, i]) and rowB = i*20+j (factor v[:, i, j]),
// in np.triu_indices order: (0,1),(0,2),...,(0,19),(1,2),...
struct PairTab {
    unsigned int rows[N_PAIRS];
    constexpr PairTab() : rows() {
        int p = 0;
        for (int i = 0; i < N_FIELDS; ++i)
            for (int j = i + 1; j < N_FIELDS; ++j) {
                rows[p++] = (unsigned int)(((j * N_FIELDS + i) << 16) |
                                            (i * N_FIELDS + j));
            }
    }
};
__constant__ PairTab TAB = PairTab();

__global__ __launch_bounds__(256)
void ffm_pair_mul_kernel(const f32x4* __restrict__ in4, f32x4* __restrict__ out4) {
    // blockIdx.y = batch index b; blockIdx.x covers the 3040 float4 outputs of b.
    const int idx = blockIdx.x * 256 + (int)threadIdx.x;  // [0, 3072), tail-guarded
    if (idx >= OUT_F4) return;

    const int p  = idx >> 4;      // pair index [0,190)
    const int e4 = idx & 15;      // float4 index within the embedding row

    const unsigned int rr = TAB.rows[p];
    const int rowA = (int)(rr >> 16);
    const int rowB = (int)(rr & 0xffffu);

    const size_t base = (size_t)blockIdx.y * IN_F4;
    // Streaming data, zero reuse: non-temporal load/store keeps L2/L3 clean.
    const f32x4 a = __builtin_nontemporal_load(&in4[base + (size_t)(rowA * ROW_F4 + e4)]);
    const f32x4 b = __builtin_nontemporal_load(&in4[base + (size_t)(rowB * ROW_F4 + e4)]);

    const f32x4 o = a * b;

    __builtin_nontemporal_store(o, &out4[(size_t)blockIdx.y * OUT_F4 + idx]);
}

extern "C" void kernel_launch(void* const* d_in, const int* in_sizes, int n_in,
                              void* d_out, int out_size, void* d_ws, size_t ws_size,
                              hipStream_t stream) {
    const f32x4* in4  = (const f32x4*)d_in[0];
    f32x4*       out4 = (f32x4*)d_out;

    // 3040 float4 per batch -> 12 blocks of 256 threads; 4096 batches in grid.y
    dim3 grid((OUT_F4 + 255) / 256, BATCH, 1);
    dim3 block(256, 1, 1);
    ffm_pair_mul_kernel<<<grid, block, 0, stream>>>(in4, out4);
}